// Round 11
// baseline (347.490 us; speedup 1.0000x reference)
//
#include <hip/hip_runtime.h>
#include <cstddef>

// ---------------------------------------------------------------------------
// CNN1D_LSTM1 pipeline, round 20: fuse conv2+branch -> c2br (5 -> 4 dispatches)
//   prep:   conv1 effective-weight pack (bf16 B-fragments) + b_eff
//   conv1p: conv 16->32 k30 MFMA + fused maxpool(k20,s5,ceil) -> S2b bf16
//   c2br:   grid 64 (b), 1024 thr.  Phase 1: conv2 (13 ltiles in 4 rounds,
//           4 tile-groups x 4 waves, same per-tile code as before) -> S3.
//           Phase 2: branch br=0 then br=1 (same bodies as before) -> Xg.
//           LDS union: conv2 {Wl 51K, At[4] 26K} / branch {bufs,Ps,xcs 95K}.
//   lstm:   r18 unchanged (92 us measured; structural floor after 6
//           alternative structures regressed).
// Discriminating experiment: non-lstm ~233us vs ~35us of estimated GPU work;
// this round removes one dispatch with ~zero GPU-work change.  Moves -> 
// overhead hypothesis confirmed; neutral -> declare structural floor.
// ---------------------------------------------------------------------------

typedef __attribute__((ext_vector_type(8))) short bf16x8;
typedef __attribute__((ext_vector_type(4))) float f32x4;
typedef unsigned int uint32;

#define LOG2E 1.4426950408889634f

__device__ __forceinline__ unsigned short f2bf(float f) {
    unsigned u = __float_as_uint(f);
    u += 0x7fffu + ((u >> 16) & 1u);   // RNE
    return (unsigned short)(u >> 16);
}
__device__ __forceinline__ float bf2f(unsigned short h) {
    return __uint_as_float(((unsigned)h) << 16);
}
__device__ __forceinline__ float exp2_(float x) {
#if __has_builtin(__builtin_amdgcn_exp2f)
    return __builtin_amdgcn_exp2f(x);
#else
    return __expf(0.6931471805599453f * x);
#endif
}
// rcp2(x) = 1/(1+2^x).  With x pre-scaled by -log2e: == sigmoid(a).
__device__ __forceinline__ float rcp2(float x) {
    return __builtin_amdgcn_rcpf(1.0f + exp2_(x));
}
__device__ __forceinline__ float sigm(float x) {
    return __builtin_amdgcn_rcpf(1.0f + __expf(-x));
}
__device__ __forceinline__ float leaky(float v) { return v >= 0.0f ? v : 0.01f * v; }

// ---------------------------------------------------------------------------
// prep: Wp1[(kc*32+n)*32 + k'] = w_eff(ch=k'&15, kappa=2kc+(k'>>4), o=n); b_eff
__global__ void prep_kernel(const float* __restrict__ w_dw, const float* __restrict__ b_dw,
                            const float* __restrict__ w_pw, const float* __restrict__ b_pw,
                            unsigned short* __restrict__ Wp1, float* __restrict__ b_eff) {
    const int bid = blockIdx.x, tid = threadIdx.x;
    if (bid < 15) {
        const int kc = bid;
        for (int it = 0; it < 4; ++it) {
            int idx = tid + it * 256;
            int n = idx >> 5, kp = idx & 31;
            int ch = kp & 15, kappa = kc * 2 + (kp >> 4);
            float s = 0.f;
            for (int j = 0; j < 16; ++j)
                s += w_pw[n * 256 + ch * 16 + j] * w_dw[(ch * 16 + j) * 30 + kappa];
            Wp1[(kc * 32 + n) * 32 + kp] = f2bf(s);
        }
    } else if (tid < 32) {
        float s = b_pw[tid];
        for (int c = 0; c < 256; ++c) s += w_pw[tid * 256 + c] * b_dw[c];
        b_eff[tid] = s;
    }
}

// ---------------------------------------------------------------------------
// conv1p: grid (26 ttiles, 64 b), 256 thr.  Tile = 32 pool outputs.
__global__ __launch_bounds__(256) void conv1p_kernel(const float* __restrict__ X,
        const unsigned short* __restrict__ Wp1, const float* __restrict__ b_eff,
        unsigned short* __restrict__ S2b, int* __restrict__ cnt) {
    const int b = blockIdx.y, tx = blockIdx.x, tid = threadIdx.x;
    if (tx == 0 && b == 0 && tid == 0) *cnt = 0;   // reset lstm completion counter
    const int l0 = tx * 160;
    __shared__ __align__(16) unsigned short Wl[480 * 40];  // B-frags, rows padded
    __shared__ __align__(16) unsigned short U[192 * 33];   // Xt[224*24] then Ct[192*33]
    unsigned short* Xt = U;
    {   // stage weights: 1920 int4 (rows 16 dw -> padded 20, 16B-aligned)
        const int4* s4 = (const int4*)Wp1;
        for (int j = tid; j < 1920; j += 256)
            *(int4*)((uint32*)Wl + (j >> 2) * 20 + (j & 3) * 4) = s4[j];
    }
    // stage X transposed bf16, float4 global loads
    for (int i = tid; i < 896; i += 256) {
        int ch = i / 56, p4 = (i - ch * 56) * 4;
        int l = l0 + p4;
        float4 v = {0.f, 0.f, 0.f, 0.f};
        const float* xrow = X + ((size_t)b * 16 + ch) * 4096;
        if (l + 3 < 4096 && p4 + 3 < 221) {
            v = *(const float4*)(xrow + l);
        } else {
            float* vv = (float*)&v;
#pragma unroll
            for (int e = 0; e < 4; ++e) {
                int p = p4 + e, le = l + e;
                vv[e] = (p < 221 && le < 4096) ? xrow[le] : 0.f;
            }
        }
        unsigned short* dst = Xt + p4 * 24 + ch;
        dst[0] = f2bf(v.x); dst[24] = f2bf(v.y); dst[48] = f2bf(v.z); dst[72] = f2bf(v.w);
    }
    __syncthreads();
    const int w = tid >> 6, lane = tid & 63, quad = lane >> 4, l16 = lane & 15;
    const int ki = quad >> 1, ch0 = (quad & 1) * 8;
    f32x4 acc[3][2];
#pragma unroll
    for (int mi = 0; mi < 3; ++mi)
#pragma unroll
        for (int nt = 0; nt < 2; ++nt) acc[mi][nt] = (f32x4){0.f, 0.f, 0.f, 0.f};
#pragma unroll
    for (int kc = 0; kc < 15; ++kc) {
        bf16x8 B0 = *(const bf16x8*)(Wl + (kc * 32 + l16) * 40 + quad * 8);
        bf16x8 B1 = *(const bf16x8*)(Wl + (kc * 32 + 16 + l16) * 40 + quad * 8);
#pragma unroll
        for (int mi = 0; mi < 3; ++mi) {
            int mrow = (w + mi * 4) * 16 + l16 + 2 * kc + ki;
            bf16x8 A = *(const bf16x8*)(Xt + mrow * 24 + ch0);
            acc[mi][0] = __builtin_amdgcn_mfma_f32_16x16x32_bf16(A, B0, acc[mi][0], 0, 0, 0);
            acc[mi][1] = __builtin_amdgcn_mfma_f32_16x16x32_bf16(A, B1, acc[mi][1], 0, 0, 0);
        }
    }
    __syncthreads();                 // all Xt reads done; reuse U as Ct
    unsigned short* Ct = U;          // [192][33]
#pragma unroll
    for (int mi = 0; mi < 3; ++mi) {
        int lrow = (w + mi * 4) * 16 + quad * 4;
#pragma unroll
        for (int nt = 0; nt < 2; ++nt) {
            int o = nt * 16 + l16;
            float be = b_eff[o];
#pragma unroll
            for (int r = 0; r < 4; ++r)
                Ct[(lrow + r) * 33 + o] = f2bf(leaky(acc[mi][nt][r] + be));
        }
    }
    __syncthreads();
    for (int idx = tid; idx < 1024; idx += 256) {    // 32 t x 32 ch
        int ti = idx >> 5, ch = idx & 31;
        int t = tx * 32 + ti;
        if (t < 811) {
            int pmax = 4067 - 5 * t; if (pmax > 20) pmax = 20;   // ceil_mode clamp
            int pbase = 5 * ti;
            float m = bf2f(Ct[pbase * 33 + ch]);
            for (int p = 1; p < pmax; ++p) m = fmaxf(m, bf2f(Ct[(pbase + p) * 33 + ch]));
            S2b[((size_t)b * 32 + ch) * 812 + t] = f2bf(m);
        }
    }
}

// ---------------------------------------------------------------------------
// c2br: fused conv2 + branch.  grid 64 (b), 1024 thr / 16 waves.
// Phase 1 (conv2): 13 ltiles in 4 rounds; tile-group g = tid>>8 (4 groups of
// 4 waves); per-tile code identical to the old conv2 with tid->t256.
// Phase 2 (branch): br=0 then br=1, bodies identical to the old branch.
// S3 stays global; intra-block write->read visibility via __syncthreads.
__global__ __launch_bounds__(1024) void c2br_kernel(const unsigned short* __restrict__ S2b,
        const float* __restrict__ w_c2, const float* __restrict__ b_c2,
        float* __restrict__ S3,
        const float* __restrict__ w_sc0, const float* __restrict__ b_sc0,
        const float* __restrict__ w_ih0, const float* __restrict__ b_ih0, const float* __restrict__ b_hh0,
        const float* __restrict__ w_sc1, const float* __restrict__ b_sc1,
        const float* __restrict__ w_ih1, const float* __restrict__ b_ih1, const float* __restrict__ b_hh1,
        float* __restrict__ Xg0, float* __restrict__ Xg1) {
    const int b = blockIdx.x, tid = threadIdx.x;

    __shared__ __align__(16) union SmemU {
        struct { unsigned short Wl[10 * 64 * 40]; unsigned short At[4][80 * 40]; } c2;
        struct { float bufs[16][2][402]; unsigned short Ps[64][302]; float xcs[4][304]; } br;
    } U;

    // ---------------- Phase 1: conv2 ----------------
    {
        const int g = tid >> 8, t256 = tid & 255;
        // stage packed weights once (same packing as old conv2)
        for (int pair = tid; pair < 2048; pair += 1024) {   // (n, kp=ch) pairs
            int n = pair >> 5, kp = pair & 31;
            const float* src = w_c2 + n * 320 + kp * 10;
            unsigned short* dstc = U.c2.Wl + n * 40 + kp;
#pragma unroll
            for (int kc = 0; kc < 10; ++kc) dstc[kc * 2560] = f2bf(src[kc]);
        }
        for (int r = 0; r < 4; ++r) {
            const int lt = r * 4 + g;
            const int l0 = lt * 64;
            if (lt < 13) {
                unsigned short* At = U.c2.At[g];
                for (int i = t256; i < 2560; i += 256) {
                    int ch = i / 80, p = i - ch * 80;
                    int l = l0 + p;
                    At[p * 40 + ch] = (p < 73 && l < 811)
                        ? S2b[((size_t)b * 32 + ch) * 812 + l] : (unsigned short)0;
                }
            }
            __syncthreads();   // Wl + this round's At ready
            if (lt < 13) {
                const unsigned short* At = U.c2.At[g];
                const int w = t256 >> 6, lane = t256 & 63, quad = lane >> 4, l16 = lane & 15;
                const int mA = w * 16 + l16, ch0 = quad * 8;
                f32x4 acc[4];
#pragma unroll
                for (int nt = 0; nt < 4; ++nt) acc[nt] = (f32x4){0.f, 0.f, 0.f, 0.f};
#pragma unroll
                for (int kc = 0; kc < 10; ++kc) {
                    bf16x8 A = *(const bf16x8*)(At + (mA + kc) * 40 + ch0);
#pragma unroll
                    for (int nt = 0; nt < 4; ++nt) {
                        bf16x8 Bf = *(const bf16x8*)(U.c2.Wl + (kc * 64 + nt * 16 + l16) * 40 + quad * 8);
                        acc[nt] = __builtin_amdgcn_mfma_f32_16x16x32_bf16(A, Bf, acc[nt], 0, 0, 0);
                    }
                }
                const int lbase = l0 + w * 16 + quad * 4;
#pragma unroll
                for (int nt = 0; nt < 4; ++nt) {
                    int o = nt * 16 + l16;
                    float bc = b_c2[o];
#pragma unroll
                    for (int r2 = 0; r2 < 4; ++r2) {
                        int l = lbase + r2;
                        if (l < 802) S3[((size_t)b * 64 + o) * 802 + l] = leaky(acc[nt][r2] + bc);
                    }
                }
            }
            __syncthreads();   // MFMA reads done before next round restages At
        }
    }

    // ---------------- Phase 2: branch (br=0 then br=1) ----------------
    const int wv = tid >> 6, lane = tid & 63;
    for (int brv = 0; brv < 2; ++brv) {
        __syncthreads();   // LDS union transition / previous-br readers done
        const int T = brv ? 100 : 300;
        const float* w_sc = brv ? w_sc1 : w_sc0;
        const float* b_sc = brv ? b_sc1 : b_sc0;
        const float* w_ih = brv ? w_ih1 : w_ih0;
        const float* b_ih = brv ? b_ih1 : b_ih0;
        const float* b_hh = brv ? b_hh1 : b_hh0;
        float* Xg = brv ? Xg1 : Xg0;

        for (int ci = 0; ci < 4; ++ci) {
            const int c = wv * 4 + ci;
            const float* row = S3 + ((size_t)b * 64 + c) * 802;
            if (brv == 0) {
                // bin=300: s=2, k=204 == max over 102 pair-maxes
                float* A = U.br.bufs[wv][0];
                float* B = U.br.bufs[wv][1];
                for (int it = 0; it < 7; ++it) {
                    int q = lane + it * 64;
                    if (q < 401) A[q] = fmaxf(row[2 * q], row[2 * q + 1]);
                }
                int len = 401;
#pragma unroll
                for (int sp = 1; sp <= 32; sp <<= 1) {     // doubling -> max of 64
                    int nl = len - sp;
                    for (int it = 0; it < 7; ++it) {
                        int q = lane + it * 64;
                        if (q < nl) B[q] = fmaxf(A[q], A[q + sp]);
                    }
                    float* tmp = A; A = B; B = tmp; len = nl;
                }
                for (int it = 0; it < 5; ++it) {           // 102 = [t,t+64)U[t+38,t+102)
                    int t = lane + it * 64;
                    if (t < 300) U.br.Ps[c][1 + t] = f2bf(fmaxf(A[t], A[t + 38]));
                }
                if (lane < 2) U.br.Ps[c][lane * 301] = 0;
            } else {
                // bin=100: s=8, k=10 direct
                for (int it = 0; it < 2; ++it) {
                    int t = lane + it * 64;
                    if (t < 100) {
                        float m = row[8 * t];
#pragma unroll
                        for (int p = 1; p < 10; ++p) m = fmaxf(m, row[8 * t + p]);
                        U.br.Ps[c][1 + t] = f2bf(m);
                    }
                }
                if (lane < 2) U.br.Ps[c][lane * 101] = 0;
            }
        }
        __syncthreads();
        // conv k=3 p=1 + leaky -> xcs LDS
        for (int i = tid; i < 4 * T; i += 1024) {
            int o = i / T, t = i - o * T;
            float sum = b_sc[o];
            const float* wvp = w_sc + o * 192;
            for (int c = 0; c < 64; ++c) {
                float p0 = bf2f(U.br.Ps[c][t]), p1 = bf2f(U.br.Ps[c][t + 1]), p2 = bf2f(U.br.Ps[c][t + 2]);
                sum += wvp[c * 3] * p0 + wvp[c * 3 + 1] * p1 + wvp[c * 3 + 2] * p2;
            }
            U.br.xcs[o][t] = leaky(sum);
        }
        __syncthreads();
        // Xg phase: thread = (h = tid&63, tq = tid>>6); one float4 store per slot
        {
            const int h = tid & 63, tq = tid >> 6;
            const int wv2 = h >> 4, l16 = h & 15;
            const int bt = b >> 2, q = b & 3;
            const float4 w0 = *(const float4*)(w_ih + (0 * 64 + h) * 4);
            const float4 w1 = *(const float4*)(w_ih + (1 * 64 + h) * 4);
            const float4 w2 = *(const float4*)(w_ih + (2 * 64 + h) * 4);
            const float4 w3 = *(const float4*)(w_ih + (3 * 64 + h) * 4);
            const float b0 = b_ih[0 * 64 + h] + b_hh[0 * 64 + h];
            const float b1 = b_ih[1 * 64 + h] + b_hh[1 * 64 + h];
            const float b2 = b_ih[2 * 64 + h] + b_hh[2 * 64 + h];
            const float b3 = b_ih[3 * 64 + h] + b_hh[3 * 64 + h];
            const float scA = -LOG2E, scG = -2.0f * LOG2E;
            float4* Xg4 = (float4*)Xg;
            const size_t slot = ((size_t)(bt * 4 + wv2) * 4 + q) * 16 + l16;
            for (int t = tq; t < T; t += 16) {
                float x0 = U.br.xcs[0][t], x1 = U.br.xcs[1][t];
                float x2 = U.br.xcs[2][t], x3 = U.br.xcs[3][t];
                float v0 = b0 + w0.x * x0 + w0.y * x1 + w0.z * x2 + w0.w * x3;
                float v1 = b1 + w1.x * x0 + w1.y * x1 + w1.z * x2 + w1.w * x3;
                float v2 = b2 + w2.x * x0 + w2.y * x1 + w2.z * x2 + w2.w * x3;
                float v3 = b3 + w3.x * x0 + w3.y * x1 + w3.z * x2 + w3.w * x3;
                float4 ov = {scA * v0, scA * v1, scG * v2, scA * v3};
                Xg4[(size_t)t * 4096 + slot] = ov;
            }
        }
    }
}

// ---------------------------------------------------------------------------
// lstm (+fused head): grid (16 bt, 2 br), 256 thr, 1 wave/SIMD.  (r18)
// Batch tile = 4, placed at MFMA rows {0,4,8,12} (r=0 of each quad):
// one activation cell per lane.  Per-step fence: ONE inline asm
// {s_waitcnt lgkmcnt(0); s_barrier} with "memory" clobber (no vmcnt drain,
// no LDS op can cross).  Tail: h = fma(2*ov, rr, -ov).
#define HPAD 72
__global__ __launch_bounds__(256) void lstm_kernel(
    const float* __restrict__ Xg0, const float* __restrict__ Xg1,
    const float* __restrict__ Whh0, const float* __restrict__ Whh1,
    const float* __restrict__ wl0, const float* __restrict__ bl0,
    const float* __restrict__ wl1, const float* __restrict__ bl1,
    float* __restrict__ brbuf, int* __restrict__ cnt,
    const float* __restrict__ w_rul, const float* __restrict__ b_rul,
    float* __restrict__ out) {
    const int bt = blockIdx.x;            // 16 batch tiles of 4
    const int br = blockIdx.y;
    const int T = (br == 0) ? 300 : 100;
    const float* Xg = (br == 0) ? Xg0 : Xg1;
    const float* Whh = (br == 0) ? Whh0 : Whh1;
    const float* wl = (br == 0) ? wl0 : wl1;
    const float* bl = (br == 0) ? bl0 : bl1;
    const float C2L = -2.0f * LOG2E;

    __shared__ __align__(16) unsigned short h_lds[2][16][HPAD];
    __shared__ int lastf;

    const int tid = threadIdx.x;
    const int w = tid >> 6, lane = tid & 63, quad = lane >> 4, l16 = lane & 15;
    const int hidx = w * 16 + l16;

    bf16x8 Bf[4][2];
#pragma unroll
    for (int g = 0; g < 4; ++g) {
        const int n = g * 64 + hidx;
        const float scg = (g == 2) ? (-2.0f * LOG2E) : (-LOG2E);
#pragma unroll
        for (int kc = 0; kc < 2; ++kc) {
            const float* src = Whh + n * 64 + kc * 32 + quad * 8;
            bf16x8 v;
#pragma unroll
            for (int j = 0; j < 8; ++j) v[j] = (short)f2bf(src[j] * scg);
            Bf[g][kc] = v;
        }
    }

    // zero BOTH h buffers: only rows {0,4,8,12} are ever written, the rest
    // must stay zero so dead A-rows contribute exactly 0.
    for (int i = tid; i < 2 * 16 * HPAD; i += 256) (&h_lds[0][0][0])[i] = 0;

    // per-lane gate slot: batch bt*4+quad, hidden hidx, gates g=0..3 contiguous
    const float* xp = Xg + (((size_t)bt * 4 + w) * 4 + quad) * 64 + l16 * 4;

    f32x4 xq[4];
#pragma unroll
    for (int j = 0; j < 4; ++j) xq[j] = *(const f32x4*)(xp + (size_t)j * 16384);

    float c0 = 0.f;

    __syncthreads();   // once: h_lds zero-init visible (full drain OK here)

    auto step = [&](int t, f32x4& xb) {
        const unsigned short* hrow = &h_lds[t & 1][l16][0];
        bf16x8 A0 = *(const bf16x8*)(hrow + quad * 8);
        bf16x8 A1 = *(const bf16x8*)(hrow + 32 + quad * 8);
        const f32x4 z = {0.f, 0.f, 0.f, 0.f};
        f32x4 ac[4];
#pragma unroll
        for (int g = 0; g < 4; ++g) {
            ac[g] = __builtin_amdgcn_mfma_f32_16x16x32_bf16(A0, Bf[g][0], z, 0, 0, 0);
            ac[g] = __builtin_amdgcn_mfma_f32_16x16x32_bf16(A1, Bf[g][1], ac[g], 0, 0, 0);
        }
        float iv = rcp2(ac[0][0] + xb[0]);                 // sigm(i)
        float fv = rcp2(ac[1][0] + xb[1]);                 // sigm(f)
        float gv = 2.0f * rcp2(ac[2][0] + xb[2]) - 1.0f;   // tanh(g)
        float ov = rcp2(ac[3][0] + xb[3]);                 // sigm(o)
        if (t + 4 < T) xb = *(const f32x4*)(xp + (size_t)(t + 4) * 16384);
        float cs = fv * c0 + iv * gv;
        c0 = cs;
        float rr = __builtin_amdgcn_rcpf(1.0f + exp2_(cs * C2L));
        float hv = fmaf(2.0f * ov, rr, -ov);               // ov*tanh(c), 1 op less
        h_lds[(t + 1) & 1][quad * 4][hidx] = f2bf(hv);
        // LDS-only fence + barrier in ONE asm (memory clobber: no LDS op can
        // cross; no vmcnt drain so the Xg ring stays in flight).
        asm volatile("s_waitcnt lgkmcnt(0)\n\ts_barrier" ::: "memory");
    };

    for (int t = 0; t < T; t += 4) {   // T % 4 == 0
#pragma unroll
        for (int j = 0; j < 4; ++j) step(t + j, xq[j]);
    }

    __syncthreads();   // full barrier once before the head

    // final linear -> brbuf (device-scope atomic stores); batch q at row 4q
    if (tid < 4) {
        const unsigned short* hrow = &h_lds[0][tid * 4][0];
        float s = bl[0];
        for (int j = 0; j < 64; ++j) s += bf2f(hrow[j]) * wl[j];
        atomicExch(&brbuf[br * 64 + bt * 4 + tid], s);
    }
    __syncthreads();
    __threadfence();
    if (tid == 0) {
        int old = atomicAdd(cnt, 1);
        lastf = (old == 31);
    }
    __syncthreads();
    if (lastf) {                       // last block computes the head
        __threadfence();
        if (tid < 64) {
            float v0 = atomicAdd(&brbuf[tid], 0.0f);        // atomic load
            float v1 = atomicAdd(&brbuf[64 + tid], 0.0f);
            float v = w_rul[0] * v0 + w_rul[1] * v1 + b_rul[0];
            out[tid] = sigm(v);
        }
    }
}

// ---------------------------------------------------------------------------
extern "C" void kernel_launch(void* const* d_in, const int* in_sizes, int n_in,
                              void* d_out, int out_size, void* d_ws, size_t ws_size,
                              hipStream_t stream) {
    const float* X     = (const float*)d_in[0];
    const float* w_dw  = (const float*)d_in[1];
    const float* b_dw  = (const float*)d_in[2];
    const float* w_pw  = (const float*)d_in[3];
    const float* b_pw  = (const float*)d_in[4];
    const float* w_c2  = (const float*)d_in[5];
    const float* b_c2  = (const float*)d_in[6];
    const float* w_sc0 = (const float*)d_in[7];
    const float* b_sc0 = (const float*)d_in[8];
    const float* w_ih0 = (const float*)d_in[9];
    const float* b_ih0 = (const float*)d_in[10];
    const float* w_hh0 = (const float*)d_in[11];
    const float* b_hh0 = (const float*)d_in[12];
    const float* w_l0  = (const float*)d_in[13];
    const float* b_l0  = (const float*)d_in[14];
    const float* w_sc1 = (const float*)d_in[15];
    const float* b_sc1 = (const float*)d_in[16];
    const float* w_ih1 = (const float*)d_in[17];
    const float* b_ih1 = (const float*)d_in[18];
    const float* w_hh1 = (const float*)d_in[19];
    const float* b_hh1 = (const float*)d_in[20];
    const float* w_l1  = (const float*)d_in[21];
    const float* b_l1  = (const float*)d_in[22];
    const float* w_rul = (const float*)d_in[23];
    const float* b_rul = (const float*)d_in[24];

    float* ws = (float*)d_ws;
    float* Xg0 = ws;                                           // 4,915,200 f
    float* Xg1 = ws + 4915200;                                 // 1,638,400 f
    unsigned short* S2b = (unsigned short*)(ws + 6553600);     // 64*32*812 sh
    float* S3    = ws + 7385088;                               // 3,284,992 f
    unsigned short* Wp1 = (unsigned short*)(ws + 10670080);    // 15,360 sh
    float* b_eff = ws + 10677760;                              // 32
    float* brbuf = ws + 10677792;                              // 128
    int*   cnt   = (int*)(ws + 10677920);                      // 1  (~42.7 MB)

    prep_kernel<<<16, 256, 0, stream>>>(w_dw, b_dw, w_pw, b_pw, Wp1, b_eff);
    conv1p_kernel<<<dim3(26, 64), 256, 0, stream>>>(X, Wp1, b_eff, S2b, cnt);
    c2br_kernel<<<64, 1024, 0, stream>>>(S2b, w_c2, b_c2, S3,
        w_sc0, b_sc0, w_ih0, b_ih0, b_hh0,
        w_sc1, b_sc1, w_ih1, b_ih1, b_hh1, Xg0, Xg1);
    lstm_kernel<<<dim3(16, 2), 256, 0, stream>>>(Xg0, Xg1, w_hh0, w_hh1,
                                                 w_l0, b_l0, w_l1, b_l1,
                                                 brbuf, cnt, w_rul, b_rul, (float*)d_out);
}

// Round 12
// 322.581 us; speedup vs baseline: 1.0772x; 1.0772x over previous
//
#include <hip/hip_runtime.h>
#include <cstddef>

// ---------------------------------------------------------------------------
// CNN1D_LSTM1 pipeline, round 21: r19 structure + conv2 staging fixes
//   prep:   conv1 weight pack + b_eff + NEW: conv2 weight pack Wp2
//           (Wp2[(kc*64+n)*32+kp] = f2bf(w_c2[n*320+kp*10+kc]))
//   conv1p: conv 16->32 k30 MFMA + fused maxpool -> S2b bf16 (unchanged)
//   conv2:  stages Wl from Wp2 via 10 coalesced int4 loads/thread (was 80
//           scattered 40B-stride scalar loads + converts: ~40 sectors/wave-ld,
//           ~680MB effective L2 traffic across 832 blocks); At staged via
//           ushort4 (was 10 scalar 2B loads + int-div indexing).
//   branch: r19 unchanged
//   lstm:   r18 unchanged (92us; structural floor)
// r20's fusion regressed (1 block/CU, 64 CUs) but localized the budget:
// conv2+branch ~ 85-90us.  This round attacks conv2's staging redundancy.
// ---------------------------------------------------------------------------

typedef __attribute__((ext_vector_type(8))) short bf16x8;
typedef __attribute__((ext_vector_type(4))) float f32x4;
typedef unsigned int uint32;

#define LOG2E 1.4426950408889634f

__device__ __forceinline__ unsigned short f2bf(float f) {
    unsigned u = __float_as_uint(f);
    u += 0x7fffu + ((u >> 16) & 1u);   // RNE
    return (unsigned short)(u >> 16);
}
__device__ __forceinline__ float bf2f(unsigned short h) {
    return __uint_as_float(((unsigned)h) << 16);
}
__device__ __forceinline__ float exp2_(float x) {
#if __has_builtin(__builtin_amdgcn_exp2f)
    return __builtin_amdgcn_exp2f(x);
#else
    return __expf(0.6931471805599453f * x);
#endif
}
// rcp2(x) = 1/(1+2^x).  With x pre-scaled by -log2e: == sigmoid(a).
__device__ __forceinline__ float rcp2(float x) {
    return __builtin_amdgcn_rcpf(1.0f + exp2_(x));
}
__device__ __forceinline__ float sigm(float x) {
    return __builtin_amdgcn_rcpf(1.0f + __expf(-x));
}
__device__ __forceinline__ float leaky(float v) { return v >= 0.0f ? v : 0.01f * v; }

// ---------------------------------------------------------------------------
// prep: bid<15: Wp1 (conv1 eff-weight pack); bid==15: b_eff;
//       bid>=16 (10 blocks): Wp2 conv2 weight pack, coalesced stores.
__global__ void prep_kernel(const float* __restrict__ w_dw, const float* __restrict__ b_dw,
                            const float* __restrict__ w_pw, const float* __restrict__ b_pw,
                            const float* __restrict__ w_c2,
                            unsigned short* __restrict__ Wp1, float* __restrict__ b_eff,
                            unsigned short* __restrict__ Wp2) {
    const int bid = blockIdx.x, tid = threadIdx.x;
    if (bid < 15) {
        const int kc = bid;
        for (int it = 0; it < 4; ++it) {
            int idx = tid + it * 256;
            int n = idx >> 5, kp = idx & 31;
            int ch = kp & 15, kappa = kc * 2 + (kp >> 4);
            float s = 0.f;
            for (int j = 0; j < 16; ++j)
                s += w_pw[n * 256 + ch * 16 + j] * w_dw[(ch * 16 + j) * 30 + kappa];
            Wp1[(kc * 32 + n) * 32 + kp] = f2bf(s);
        }
    } else if (bid == 15) {
        if (tid < 32) {
            float s = b_pw[tid];
            for (int c = 0; c < 256; ++c) s += w_pw[tid * 256 + c] * b_dw[c];
            b_eff[tid] = s;
        }
    } else {
        // Wp2[(kc*64+n)*32+kp] = f2bf(w_c2[n*320 + kp*10 + kc]); 20480 total
        const int base = (bid - 16) * 2048;
#pragma unroll
        for (int e = 0; e < 8; ++e) {
            int flat = base + tid + e * 256;
            int kp = flat & 31, rest = flat >> 5;
            int n = rest & 63, kc = rest >> 6;
            Wp2[flat] = f2bf(w_c2[n * 320 + kp * 10 + kc]);
        }
    }
}

// ---------------------------------------------------------------------------
// conv1p: grid (26 ttiles, 64 b), 256 thr.  Tile = 32 pool outputs.
__global__ __launch_bounds__(256) void conv1p_kernel(const float* __restrict__ X,
        const unsigned short* __restrict__ Wp1, const float* __restrict__ b_eff,
        unsigned short* __restrict__ S2b, int* __restrict__ cnt) {
    const int b = blockIdx.y, tx = blockIdx.x, tid = threadIdx.x;
    if (tx == 0 && b == 0 && tid == 0) *cnt = 0;   // reset lstm completion counter
    const int l0 = tx * 160;
    __shared__ __align__(16) unsigned short Wl[480 * 40];  // B-frags, rows padded
    __shared__ __align__(16) unsigned short U[192 * 33];   // Xt[224*24] then Ct[192*33]
    unsigned short* Xt = U;
    {   // stage weights: 1920 int4 (rows 16 dw -> padded 20, 16B-aligned)
        const int4* s4 = (const int4*)Wp1;
        for (int j = tid; j < 1920; j += 256)
            *(int4*)((uint32*)Wl + (j >> 2) * 20 + (j & 3) * 4) = s4[j];
    }
    // stage X transposed bf16, float4 global loads
    for (int i = tid; i < 896; i += 256) {
        int ch = i / 56, p4 = (i - ch * 56) * 4;
        int l = l0 + p4;
        float4 v = {0.f, 0.f, 0.f, 0.f};
        const float* xrow = X + ((size_t)b * 16 + ch) * 4096;
        if (l + 3 < 4096 && p4 + 3 < 221) {
            v = *(const float4*)(xrow + l);
        } else {
            float* vv = (float*)&v;
#pragma unroll
            for (int e = 0; e < 4; ++e) {
                int p = p4 + e, le = l + e;
                vv[e] = (p < 221 && le < 4096) ? xrow[le] : 0.f;
            }
        }
        unsigned short* dst = Xt + p4 * 24 + ch;
        dst[0] = f2bf(v.x); dst[24] = f2bf(v.y); dst[48] = f2bf(v.z); dst[72] = f2bf(v.w);
    }
    __syncthreads();
    const int w = tid >> 6, lane = tid & 63, quad = lane >> 4, l16 = lane & 15;
    const int ki = quad >> 1, ch0 = (quad & 1) * 8;
    f32x4 acc[3][2];
#pragma unroll
    for (int mi = 0; mi < 3; ++mi)
#pragma unroll
        for (int nt = 0; nt < 2; ++nt) acc[mi][nt] = (f32x4){0.f, 0.f, 0.f, 0.f};
#pragma unroll
    for (int kc = 0; kc < 15; ++kc) {
        bf16x8 B0 = *(const bf16x8*)(Wl + (kc * 32 + l16) * 40 + quad * 8);
        bf16x8 B1 = *(const bf16x8*)(Wl + (kc * 32 + 16 + l16) * 40 + quad * 8);
#pragma unroll
        for (int mi = 0; mi < 3; ++mi) {
            int mrow = (w + mi * 4) * 16 + l16 + 2 * kc + ki;
            bf16x8 A = *(const bf16x8*)(Xt + mrow * 24 + ch0);
            acc[mi][0] = __builtin_amdgcn_mfma_f32_16x16x32_bf16(A, B0, acc[mi][0], 0, 0, 0);
            acc[mi][1] = __builtin_amdgcn_mfma_f32_16x16x32_bf16(A, B1, acc[mi][1], 0, 0, 0);
        }
    }
    __syncthreads();                 // all Xt reads done; reuse U as Ct
    unsigned short* Ct = U;          // [192][33]
#pragma unroll
    for (int mi = 0; mi < 3; ++mi) {
        int lrow = (w + mi * 4) * 16 + quad * 4;
#pragma unroll
        for (int nt = 0; nt < 2; ++nt) {
            int o = nt * 16 + l16;
            float be = b_eff[o];
#pragma unroll
            for (int r = 0; r < 4; ++r)
                Ct[(lrow + r) * 33 + o] = f2bf(leaky(acc[mi][nt][r] + be));
        }
    }
    __syncthreads();
    for (int idx = tid; idx < 1024; idx += 256) {    // 32 t x 32 ch
        int ti = idx >> 5, ch = idx & 31;
        int t = tx * 32 + ti;
        if (t < 811) {
            int pmax = 4067 - 5 * t; if (pmax > 20) pmax = 20;   // ceil_mode clamp
            int pbase = 5 * ti;
            float m = bf2f(Ct[pbase * 33 + ch]);
            for (int p = 1; p < pmax; ++p) m = fmaxf(m, bf2f(Ct[(pbase + p) * 33 + ch]));
            S2b[((size_t)b * 32 + ch) * 812 + t] = f2bf(m);
        }
    }
}

// ---------------------------------------------------------------------------
// conv2: grid (13 ltiles, 64 b).  M=64, N=64, K=320.
// r21: Wl staged from pre-packed Wp2 via int4 (10/thread, coalesced);
//      At staged via ushort4 (3 passes, 8 lanes = 64B contiguous).
__global__ __launch_bounds__(256) void conv2_kernel(const unsigned short* __restrict__ S2b,
        const unsigned short* __restrict__ Wp2, const float* __restrict__ b_c2,
        float* __restrict__ S3) {
    const int b = blockIdx.y, l0 = blockIdx.x * 64, tid = threadIdx.x;
    __shared__ __align__(16) unsigned short At[80 * 40];
    __shared__ __align__(16) unsigned short Wl[10 * 64 * 40];
    {   // stage weights: 2560 int4 (640 rows of 32 shorts -> padded 40)
        const int4* s4 = (const int4*)Wp2;
        for (int j = tid; j < 2560; j += 256)
            *(int4*)((uint32*)Wl + (j >> 2) * 20 + (j & 3) * 4) = s4[j];
    }
    {   // stage At: thread=(ch=tid>>3, p4=(tid&7)+8*pass); ushort4 loads
        const int ch = tid >> 3;
        const unsigned short* srow = S2b + ((size_t)b * 32 + ch) * 812;
#pragma unroll
        for (int pass = 0; pass < 3; ++pass) {
            int p4 = (tid & 7) + pass * 8;
            if (p4 < 20) {
                int p = p4 * 4, l = l0 + p;
                if (p + 3 < 73 && l + 3 < 811) {
                    ushort4 v = *(const ushort4*)(srow + l);
                    At[p * 40 + ch] = v.x;
                    At[(p + 1) * 40 + ch] = v.y;
                    At[(p + 2) * 40 + ch] = v.z;
                    At[(p + 3) * 40 + ch] = v.w;
                } else {
#pragma unroll
                    for (int e = 0; e < 4; ++e) {
                        int pe = p + e, le = l + e;
                        At[pe * 40 + ch] = (pe < 73 && le < 811) ? srow[le] : (unsigned short)0;
                    }
                }
            }
        }
    }
    __syncthreads();
    const int w = tid >> 6, lane = tid & 63, quad = lane >> 4, l16 = lane & 15;
    const int mA = w * 16 + l16, ch0 = quad * 8;
    f32x4 acc[4];
#pragma unroll
    for (int nt = 0; nt < 4; ++nt) acc[nt] = (f32x4){0.f, 0.f, 0.f, 0.f};
#pragma unroll
    for (int kc = 0; kc < 10; ++kc) {
        bf16x8 A = *(const bf16x8*)(At + (mA + kc) * 40 + ch0);
#pragma unroll
        for (int nt = 0; nt < 4; ++nt) {
            bf16x8 Bf = *(const bf16x8*)(Wl + (kc * 64 + nt * 16 + l16) * 40 + quad * 8);
            acc[nt] = __builtin_amdgcn_mfma_f32_16x16x32_bf16(A, Bf, acc[nt], 0, 0, 0);
        }
    }
    const int lbase = l0 + w * 16 + quad * 4;
#pragma unroll
    for (int nt = 0; nt < 4; ++nt) {
        int o = nt * 16 + l16;
        float bc = b_c2[o];
#pragma unroll
        for (int r = 0; r < 4; ++r) {
            int l = lbase + r;
            if (l < 802) S3[((size_t)b * 64 + o) * 802 + l] = leaky(acc[nt][r] + bc);
        }
    }
}

// ---------------------------------------------------------------------------
// branch: adaptive maxpool + conv(64->4,k3,p1)+leaky + Xg precompute+store.
// grid (64 b, 2 br), 1024 thr.  (r19 unchanged)
__global__ __launch_bounds__(1024) void branch_kernel(const float* __restrict__ S3,
        const float* __restrict__ w_sc0, const float* __restrict__ b_sc0,
        const float* __restrict__ w_ih0, const float* __restrict__ b_ih0, const float* __restrict__ b_hh0,
        const float* __restrict__ w_sc1, const float* __restrict__ b_sc1,
        const float* __restrict__ w_ih1, const float* __restrict__ b_ih1, const float* __restrict__ b_hh1,
        float* __restrict__ Xg0, float* __restrict__ Xg1) {
    const int b = blockIdx.x, br = blockIdx.y;
    const int T = br ? 100 : 300;
    const float* w_sc = br ? w_sc1 : w_sc0;
    const float* b_sc = br ? b_sc1 : b_sc0;
    const float* w_ih = br ? w_ih1 : w_ih0;
    const float* b_ih = br ? b_ih1 : b_ih0;
    const float* b_hh = br ? b_hh1 : b_hh0;
    float* Xg = br ? Xg1 : Xg0;

    __shared__ float bufs[16][2][402];
    __shared__ unsigned short Ps[64][302];   // pooled rows, halo-padded
    __shared__ float xcs[4][304];
    const int tid = threadIdx.x, wv = tid >> 6, lane = tid & 63;

    for (int ci = 0; ci < 4; ++ci) {
        const int c = wv * 4 + ci;
        const float* row = S3 + ((size_t)b * 64 + c) * 802;
        if (br == 0) {
            // bin=300: s=2, k=204 == max over 102 pair-maxes
            float* A = bufs[wv][0];
            float* B = bufs[wv][1];
            for (int it = 0; it < 7; ++it) {
                int q = lane + it * 64;
                if (q < 401) A[q] = fmaxf(row[2 * q], row[2 * q + 1]);
            }
            int len = 401;
#pragma unroll
            for (int sp = 1; sp <= 32; sp <<= 1) {     // doubling -> max of 64
                int nl = len - sp;
                for (int it = 0; it < 7; ++it) {
                    int q = lane + it * 64;
                    if (q < nl) B[q] = fmaxf(A[q], A[q + sp]);
                }
                float* tmp = A; A = B; B = tmp; len = nl;
            }
            for (int it = 0; it < 5; ++it) {           // 102 = [t,t+64)U[t+38,t+102)
                int t = lane + it * 64;
                if (t < 300) Ps[c][1 + t] = f2bf(fmaxf(A[t], A[t + 38]));
            }
            if (lane < 2) Ps[c][lane * 301] = 0;
        } else {
            // bin=100: s=8, k=10 direct
            for (int it = 0; it < 2; ++it) {
                int t = lane + it * 64;
                if (t < 100) {
                    float m = row[8 * t];
#pragma unroll
                    for (int p = 1; p < 10; ++p) m = fmaxf(m, row[8 * t + p]);
                    Ps[c][1 + t] = f2bf(m);
                }
            }
            if (lane < 2) Ps[c][lane * 101] = 0;
        }
    }
    __syncthreads();
    // conv k=3 p=1 + leaky -> xcs LDS
    for (int i = tid; i < 4 * T; i += 1024) {
        int o = i / T, t = i - o * T;
        float sum = b_sc[o];
        const float* wvp = w_sc + o * 192;
        for (int c = 0; c < 64; ++c) {
            float p0 = bf2f(Ps[c][t]), p1 = bf2f(Ps[c][t + 1]), p2 = bf2f(Ps[c][t + 2]);
            sum += wvp[c * 3] * p0 + wvp[c * 3 + 1] * p1 + wvp[c * 3 + 2] * p2;
        }
        xcs[o][t] = leaky(sum);
    }
    __syncthreads();
    // Xg phase: thread = (h = tid&63, tq = tid>>6); one float4 store per slot
    {
        const int h = tid & 63, tq = tid >> 6;
        const int wv2 = h >> 4, l16 = h & 15;
        const int bt = b >> 2, q = b & 3;
        const float4 w0 = *(const float4*)(w_ih + (0 * 64 + h) * 4);
        const float4 w1 = *(const float4*)(w_ih + (1 * 64 + h) * 4);
        const float4 w2 = *(const float4*)(w_ih + (2 * 64 + h) * 4);
        const float4 w3 = *(const float4*)(w_ih + (3 * 64 + h) * 4);
        const float b0 = b_ih[0 * 64 + h] + b_hh[0 * 64 + h];
        const float b1 = b_ih[1 * 64 + h] + b_hh[1 * 64 + h];
        const float b2 = b_ih[2 * 64 + h] + b_hh[2 * 64 + h];
        const float b3 = b_ih[3 * 64 + h] + b_hh[3 * 64 + h];
        const float scA = -LOG2E, scG = -2.0f * LOG2E;
        float4* Xg4 = (float4*)Xg;
        const size_t slot = ((size_t)(bt * 4 + wv2) * 4 + q) * 16 + l16;
        for (int t = tq; t < T; t += 16) {
            float x0 = xcs[0][t], x1 = xcs[1][t], x2 = xcs[2][t], x3 = xcs[3][t];
            float v0 = b0 + w0.x * x0 + w0.y * x1 + w0.z * x2 + w0.w * x3;
            float v1 = b1 + w1.x * x0 + w1.y * x1 + w1.z * x2 + w1.w * x3;
            float v2 = b2 + w2.x * x0 + w2.y * x1 + w2.z * x2 + w2.w * x3;
            float v3 = b3 + w3.x * x0 + w3.y * x1 + w3.z * x2 + w3.w * x3;
            float4 ov = {scA * v0, scA * v1, scG * v2, scA * v3};
            Xg4[(size_t)t * 4096 + slot] = ov;
        }
    }
}

// ---------------------------------------------------------------------------
// lstm (+fused head): grid (16 bt, 2 br), 256 thr, 1 wave/SIMD.  (r18)
#define HPAD 72
__global__ __launch_bounds__(256) void lstm_kernel(
    const float* __restrict__ Xg0, const float* __restrict__ Xg1,
    const float* __restrict__ Whh0, const float* __restrict__ Whh1,
    const float* __restrict__ wl0, const float* __restrict__ bl0,
    const float* __restrict__ wl1, const float* __restrict__ bl1,
    float* __restrict__ brbuf, int* __restrict__ cnt,
    const float* __restrict__ w_rul, const float* __restrict__ b_rul,
    float* __restrict__ out) {
    const int bt = blockIdx.x;            // 16 batch tiles of 4
    const int br = blockIdx.y;
    const int T = (br == 0) ? 300 : 100;
    const float* Xg = (br == 0) ? Xg0 : Xg1;
    const float* Whh = (br == 0) ? Whh0 : Whh1;
    const float* wl = (br == 0) ? wl0 : wl1;
    const float* bl = (br == 0) ? bl0 : bl1;
    const float C2L = -2.0f * LOG2E;

    __shared__ __align__(16) unsigned short h_lds[2][16][HPAD];
    __shared__ int lastf;

    const int tid = threadIdx.x;
    const int w = tid >> 6, lane = tid & 63, quad = lane >> 4, l16 = lane & 15;
    const int hidx = w * 16 + l16;

    bf16x8 Bf[4][2];
#pragma unroll
    for (int g = 0; g < 4; ++g) {
        const int n = g * 64 + hidx;
        const float scg = (g == 2) ? (-2.0f * LOG2E) : (-LOG2E);
#pragma unroll
        for (int kc = 0; kc < 2; ++kc) {
            const float* src = Whh + n * 64 + kc * 32 + quad * 8;
            bf16x8 v;
#pragma unroll
            for (int j = 0; j < 8; ++j) v[j] = (short)f2bf(src[j] * scg);
            Bf[g][kc] = v;
        }
    }

    // zero BOTH h buffers: only rows {0,4,8,12} are ever written, the rest
    // must stay zero so dead A-rows contribute exactly 0.
    for (int i = tid; i < 2 * 16 * HPAD; i += 256) (&h_lds[0][0][0])[i] = 0;

    // per-lane gate slot: batch bt*4+quad, hidden hidx, gates g=0..3 contiguous
    const float* xp = Xg + (((size_t)bt * 4 + w) * 4 + quad) * 64 + l16 * 4;

    f32x4 xq[4];
#pragma unroll
    for (int j = 0; j < 4; ++j) xq[j] = *(const f32x4*)(xp + (size_t)j * 16384);

    float c0 = 0.f;

    __syncthreads();   // once: h_lds zero-init visible (full drain OK here)

    auto step = [&](int t, f32x4& xb) {
        const unsigned short* hrow = &h_lds[t & 1][l16][0];
        bf16x8 A0 = *(const bf16x8*)(hrow + quad * 8);
        bf16x8 A1 = *(const bf16x8*)(hrow + 32 + quad * 8);
        const f32x4 z = {0.f, 0.f, 0.f, 0.f};
        f32x4 ac[4];
#pragma unroll
        for (int g = 0; g < 4; ++g) {
            ac[g] = __builtin_amdgcn_mfma_f32_16x16x32_bf16(A0, Bf[g][0], z, 0, 0, 0);
            ac[g] = __builtin_amdgcn_mfma_f32_16x16x32_bf16(A1, Bf[g][1], ac[g], 0, 0, 0);
        }
        float iv = rcp2(ac[0][0] + xb[0]);                 // sigm(i)
        float fv = rcp2(ac[1][0] + xb[1]);                 // sigm(f)
        float gv = 2.0f * rcp2(ac[2][0] + xb[2]) - 1.0f;   // tanh(g)
        float ov = rcp2(ac[3][0] + xb[3]);                 // sigm(o)
        if (t + 4 < T) xb = *(const f32x4*)(xp + (size_t)(t + 4) * 16384);
        float cs = fv * c0 + iv * gv;
        c0 = cs;
        float rr = __builtin_amdgcn_rcpf(1.0f + exp2_(cs * C2L));
        float hv = fmaf(2.0f * ov, rr, -ov);               // ov*tanh(c), 1 op less
        h_lds[(t + 1) & 1][quad * 4][hidx] = f2bf(hv);
        // LDS-only fence + barrier in ONE asm (memory clobber: no LDS op can
        // cross; no vmcnt drain so the Xg ring stays in flight).
        asm volatile("s_waitcnt lgkmcnt(0)\n\ts_barrier" ::: "memory");
    };

    for (int t = 0; t < T; t += 4) {   // T % 4 == 0
#pragma unroll
        for (int j = 0; j < 4; ++j) step(t + j, xq[j]);
    }

    __syncthreads();   // full barrier once before the head

    // final linear -> brbuf (device-scope atomic stores); batch q at row 4q
    if (tid < 4) {
        const unsigned short* hrow = &h_lds[0][tid * 4][0];
        float s = bl[0];
        for (int j = 0; j < 64; ++j) s += bf2f(hrow[j]) * wl[j];
        atomicExch(&brbuf[br * 64 + bt * 4 + tid], s);
    }
    __syncthreads();
    __threadfence();
    if (tid == 0) {
        int old = atomicAdd(cnt, 1);
        lastf = (old == 31);
    }
    __syncthreads();
    if (lastf) {                       // last block computes the head
        __threadfence();
        if (tid < 64) {
            float v0 = atomicAdd(&brbuf[tid], 0.0f);        // atomic load
            float v1 = atomicAdd(&brbuf[64 + tid], 0.0f);
            float v = w_rul[0] * v0 + w_rul[1] * v1 + b_rul[0];
            out[tid] = sigm(v);
        }
    }
}

// ---------------------------------------------------------------------------
extern "C" void kernel_launch(void* const* d_in, const int* in_sizes, int n_in,
                              void* d_out, int out_size, void* d_ws, size_t ws_size,
                              hipStream_t stream) {
    const float* X     = (const float*)d_in[0];
    const float* w_dw  = (const float*)d_in[1];
    const float* b_dw  = (const float*)d_in[2];
    const float* w_pw  = (const float*)d_in[3];
    const float* b_pw  = (const float*)d_in[4];
    const float* w_c2  = (const float*)d_in[5];
    const float* b_c2  = (const float*)d_in[6];
    const float* w_sc0 = (const float*)d_in[7];
    const float* b_sc0 = (const float*)d_in[8];
    const float* w_ih0 = (const float*)d_in[9];
    const float* b_ih0 = (const float*)d_in[10];
    const float* w_hh0 = (const float*)d_in[11];
    const float* b_hh0 = (const float*)d_in[12];
    const float* w_l0  = (const float*)d_in[13];
    const float* b_l0  = (const float*)d_in[14];
    const float* w_sc1 = (const float*)d_in[15];
    const float* b_sc1 = (const float*)d_in[16];
    const float* w_ih1 = (const float*)d_in[17];
    const float* b_ih1 = (const float*)d_in[18];
    const float* w_hh1 = (const float*)d_in[19];
    const float* b_hh1 = (const float*)d_in[20];
    const float* w_l1  = (const float*)d_in[21];
    const float* b_l1  = (const float*)d_in[22];
    const float* w_rul = (const float*)d_in[23];
    const float* b_rul = (const float*)d_in[24];

    float* ws = (float*)d_ws;
    float* Xg0 = ws;                                           // 4,915,200 f
    float* Xg1 = ws + 4915200;                                 // 1,638,400 f
    unsigned short* S2b = (unsigned short*)(ws + 6553600);     // 64*32*812 sh
    float* S3    = ws + 7385088;                               // 3,284,992 f
    unsigned short* Wp1 = (unsigned short*)(ws + 10670080);    // 15,360 sh
    float* b_eff = ws + 10677760;                              // 32
    float* brbuf = ws + 10677792;                              // 128
    int*   cnt   = (int*)(ws + 10677920);                      // 1
    unsigned short* Wp2 = (unsigned short*)(ws + 10677952);    // 20,480 sh (~42.75 MB)

    prep_kernel<<<26, 256, 0, stream>>>(w_dw, b_dw, w_pw, b_pw, w_c2, Wp1, b_eff, Wp2);
    conv1p_kernel<<<dim3(26, 64), 256, 0, stream>>>(X, Wp1, b_eff, S2b, cnt);
    conv2_kernel<<<dim3(13, 64), 256, 0, stream>>>(S2b, Wp2, b_c2, S3);
    branch_kernel<<<dim3(64, 2), 1024, 0, stream>>>(
        S3, w_sc0, b_sc0, w_ih0, b_ih0, b_hh0,
            w_sc1, b_sc1, w_ih1, b_ih1, b_hh1, Xg0, Xg1);
    lstm_kernel<<<dim3(16, 2), 256, 0, stream>>>(Xg0, Xg1, w_hh0, w_hh1,
                                                 w_l0, b_l0, w_l1, b_l1,
                                                 brbuf, cnt, w_rul, b_rul, (float*)d_out);
}